// Round 4
// baseline (438.981 us; speedup 1.0000x reference)
//
#include <hip/hip_runtime.h>
#include <math.h>

// B=4096, K=64, D=128 (fp32). Row = 128 floats = 32 float4 = 512 B.
// One block per b (4096 blocks x 256 threads = 8 half-waves).
// Half-wave hw owns k = hw*8 .. hw*8+7 and issues ALL 24 row-gathers
// (8 k x {Wi,Wart,Walb}) back-to-back before any use: ~12 KB outstanding per
// half-wave, maximizing memory-level parallelism. u row held in registers.
// Wi gathers nontemporal (256 MB zero-reuse stream; keep Wart/Walb/Wu in L3).

typedef float vf4 __attribute__((ext_vector_type(4)));

__device__ __forceinline__ float halfwave_sum(float v) {
    // xor offsets 1..16 stay inside each 32-lane half of the wave64.
    #pragma unroll
    for (int off = 16; off; off >>= 1) v += __shfl_xor(v, off);
    return v;
}

__global__ __launch_bounds__(256) void cml_fused_kernel(
    const int* __restrict__ pairs,     // (B,2)
    const int* __restrict__ pos_art,   // (B,)
    const int* __restrict__ pos_alb,   // (B,)
    const int* __restrict__ neg_samp,  // (B,K)
    const int* __restrict__ neg_art,   // (B,K)
    const int* __restrict__ neg_alb,   // (B,K)
    const vf4* __restrict__ Wu,        // (N_USERS, 32)
    const vf4* __restrict__ Wi,        // (N_ITEMS, 32)
    const vf4* __restrict__ Wart,      // (N_ARTISTS, 32)
    const vf4* __restrict__ Walb,      // (N_ALBUMS, 32)
    float* __restrict__ out_pos,       // (B,)
    float* __restrict__ out_dist,      // (B,K)
    float* __restrict__ out_min,       // (B,)
    int Kn)
{
    const int b    = blockIdx.x;
    const int tid  = threadIdx.x;
    const int lane = tid & 31;   // lane within half-wave
    const int hw   = tid >> 5;   // half-wave id, 0..7

    __shared__ float s_min[8];

    // User row: lane l holds float4 element l. One 512B coalesced gather,
    // reused (in registers) across all 8 k's of this half-wave.
    const int ui = pairs[2 * b];
    const vf4 u = Wu[(size_t)ui * 32 + lane];

    // Positive distance: half-wave 0 only.
    if (hw == 0) {
        const int ii = pairs[2 * b + 1];
        const int ia = pos_art[b];
        const int il = pos_alb[b];
        const vf4 a = Wi  [(size_t)ii * 32 + lane];
        const vf4 r = Wart[(size_t)ia * 32 + lane];
        const vf4 l = Walb[(size_t)il * 32 + lane];
        const float inv3 = 1.0f / 3.0f;
        const float dx = u.x - (a.x + r.x + l.x) * inv3;
        const float dy = u.y - (a.y + r.y + l.y) * inv3;
        const float dz = u.z - (a.z + r.z + l.z) * inv3;
        const float dw = u.w - (a.w + r.w + l.w) * inv3;
        const float d = halfwave_sum(dx * dx + dy * dy + dz * dz + dw * dw);
        if (lane == 0) out_pos[b] = d;
    }

    // My half-wave's 8 indices per table: lanes 0..7 load 8 consecutive ints
    // (one 32B coalesced load each), then broadcast with __shfl width=32.
    const int kbase = b * Kn + hw * 8;
    int v_samp = 0, v_art = 0, v_alb = 0;
    if (lane < 8) {
        v_samp = neg_samp[kbase + lane];
        v_art  = neg_art [kbase + lane];
        v_alb  = neg_alb [kbase + lane];
    }

    // Issue ALL 24 row gathers back-to-back (max MLP; no dependent use until
    // all are in flight).
    vf4 A[8], R[8], L[8];
    #pragma unroll
    for (int j = 0; j < 8; ++j) {
        const int ii = __shfl(v_samp, j, 32);
        const int ia = __shfl(v_art,  j, 32);
        const int il = __shfl(v_alb,  j, 32);
        A[j] = __builtin_nontemporal_load(&Wi[(size_t)ii * 32 + lane]);
        R[j] = Wart[(size_t)ia * 32 + lane];
        L[j] = Walb[(size_t)il * 32 + lane];
    }

    float m = INFINITY;
    float myd = 0.0f;
    const float inv3 = 1.0f / 3.0f;
    #pragma unroll
    for (int j = 0; j < 8; ++j) {
        const float dx = u.x - (A[j].x + R[j].x + L[j].x) * inv3;
        const float dy = u.y - (A[j].y + R[j].y + L[j].y) * inv3;
        const float dz = u.z - (A[j].z + R[j].z + L[j].z) * inv3;
        const float dw = u.w - (A[j].w + R[j].w + L[j].w) * inv3;
        const float d = halfwave_sum(dx * dx + dy * dy + dz * dz + dw * dw);
        m = fminf(m, d);
        if (lane == j) myd = d; // lane j keeps distance j
    }
    // One coalesced 32B (8-lane) store per half-wave.
    if (lane < 8) out_dist[kbase + lane] = myd;

    if (lane == 0) s_min[hw] = m;
    __syncthreads();

    if (tid == 0) {
        float mm = s_min[0];
        #pragma unroll
        for (int i = 1; i < 8; ++i) mm = fminf(mm, s_min[i]);
        out_min[b] = mm;
    }
}

extern "C" void kernel_launch(void* const* d_in, const int* in_sizes, int n_in,
                              void* d_out, int out_size, void* d_ws, size_t ws_size,
                              hipStream_t stream) {
    const int* pairs    = (const int*)d_in[0];
    const int* pos_art  = (const int*)d_in[1];
    const int* pos_alb  = (const int*)d_in[2];
    const int* neg_samp = (const int*)d_in[3];
    const int* neg_art  = (const int*)d_in[4];
    const int* neg_alb  = (const int*)d_in[5];
    // d_in[6] titles, d_in[7] titles_len: unused by the reference math.
    const vf4* Wu   = (const vf4*)d_in[8];
    const vf4* Wi   = (const vf4*)d_in[9];
    const vf4* Wart = (const vf4*)d_in[10];
    const vf4* Walb = (const vf4*)d_in[11];

    const int Bn = in_sizes[1];            // 4096
    const int Kn = in_sizes[3] / Bn;       // 64

    float* out      = (float*)d_out;
    float* out_pos  = out;                         // (B,)
    float* out_dist = out + Bn;                    // (B,K)
    float* out_min  = out + Bn + (size_t)Bn * Kn;  // (B,)

    cml_fused_kernel<<<Bn, 256, 0, stream>>>(
        pairs, pos_art, pos_alb, neg_samp, neg_art, neg_alb,
        Wu, Wi, Wart, Walb, out_pos, out_dist, out_min, Kn);
}